// Round 1
// baseline (335.018 us; speedup 1.0000x reference)
//
#include <hip/hip_runtime.h>
#include <cstdint>
#include <cstddef>

// Problem constants (fixed by the reference)
#define T_TOK 8192
#define DIM   1024   // D
#define FF    512    // F
#define NE    8      // experts
#define NSLOT 16384  // T*K

typedef short s16x8 __attribute__((ext_vector_type(8)));   // 8 bf16 (4 VGPRs) - MFMA A/B frag
typedef float f32x4 __attribute__((ext_vector_type(4)));   // MFMA C/D frag

// f32 -> bf16 (round-to-nearest-even), returns bits in low 16
__device__ __forceinline__ unsigned int f2bf(float f) {
    union { float f; unsigned int u; } v; v.f = f;
    return (v.u + 0x7FFFu + ((v.u >> 16) & 1u)) >> 16;
}
__device__ __forceinline__ int pack2(float a, float b) {
    return (int)f2bf(a) | ((int)f2bf(b) << 16);
}
// load 8 contiguous f32, convert to 8 bf16 packed in an int4 (16B)
__device__ __forceinline__ int4 cvt8(const float* p) {
    float4 x = *(const float4*)p;
    float4 y = *(const float4*)(p + 4);
    int4 r;
    r.x = pack2(x.x, x.y); r.y = pack2(x.z, x.w);
    r.z = pack2(y.x, y.y); r.w = pack2(y.z, y.w);
    return r;
}

// ---------------- routing ----------------
__global__ void route_count(const int* __restrict__ idx, int* counts) {
    int s = blockIdx.x * 256 + threadIdx.x;
    if (s < NSLOT) atomicAdd(&counts[idx[s]], 1);
}
__global__ void route_scan(const int* __restrict__ counts, int* offsets, int* cursor) {
    if (threadIdx.x == 0) {
        int acc = 0;
        for (int e = 0; e < NE; ++e) { offsets[e] = acc; cursor[e] = acc; acc += counts[e]; }
        offsets[NE] = acc;
    }
}
__global__ void route_scatter(const int* __restrict__ idx, int* cursor, int* row_slot) {
    int s = blockIdx.x * 256 + threadIdx.x;
    if (s < NSLOT) {
        int e = idx[s];
        int p = atomicAdd(&cursor[e], 1);
        row_slot[p] = s;   // compacted row -> slot id (token = slot>>1)
    }
}

// ---------------- GEMM1: act = silu(X Wg^T) * (X Wu^T), fused ----------------
// tile: 128 rows x 64 act-cols (needs gate rows + up rows of Wgu), BK=64
// grid: (F/64, 128, NE); block: 256 threads = 4 waves (2x2)
__global__ __launch_bounds__(256) void moe_gemm1(
    const float* __restrict__ hidden,
    const float* __restrict__ gup,       // [E, 2F, D]
    const int*   __restrict__ row_slot,
    const int*   __restrict__ offsets,
    unsigned short* __restrict__ act)    // [NSLOT, F] bf16 bits
{
    const int e    = blockIdx.z;
    const int row0 = offsets[e];
    const int n_e  = offsets[e + 1] - row0;
    const int by   = blockIdx.y;
    if (by * 128 >= n_e) return;
    const int bx   = blockIdx.x;

    __shared__ __align__(16) unsigned short Abuf[128 * 64];
    __shared__ __align__(16) unsigned short Bbuf[128 * 64]; // rows 0..63 gate, 64..127 up
    char* Ab = (char*)Abuf; char* Bb = (char*)Bbuf;

    const int tid  = threadIdx.x;
    const int lane = tid & 63;
    const int wv   = tid >> 6;
    const int wr   = wv >> 1, wc = wv & 1;

    // staging descriptors: 4 x 16B chunks each for A and B
    const float* aptr[4]; const float* bptr[4]; int soff[4];
#pragma unroll
    for (int i = 0; i < 4; ++i) {
        const int chunk = tid + i * 256;
        const int r = chunk >> 3, c = chunk & 7;
        soff[i] = r * 128 + ((c ^ (r & 7)) << 4);       // XOR-swizzled LDS byte offset
        int rr = by * 128 + r; if (rr >= n_e) rr = n_e - 1;   // clamp pad rows
        const int slot = row_slot[row0 + rr];
        aptr[i] = hidden + (size_t)(slot >> 1) * DIM + c * 8;
        const int gr = (r < 64) ? (bx * 64 + r) : (FF + bx * 64 + (r - 64));
        bptr[i] = gup + (size_t)e * (2 * FF * DIM) + (size_t)gr * DIM + c * 8;
    }

    const f32x4 zf = {0.f, 0.f, 0.f, 0.f};
    f32x4 acc_g[4][2], acc_u[4][2];
#pragma unroll
    for (int m = 0; m < 4; ++m)
#pragma unroll
        for (int n = 0; n < 2; ++n) { acc_g[m][n] = zf; acc_u[m][n] = zf; }

    for (int k0 = 0; k0 < DIM; k0 += 64) {
        __syncthreads();
#pragma unroll
        for (int i = 0; i < 4; ++i) *(int4*)(Ab + soff[i]) = cvt8(aptr[i] + k0);
#pragma unroll
        for (int i = 0; i < 4; ++i) *(int4*)(Bb + soff[i]) = cvt8(bptr[i] + k0);
        __syncthreads();

#pragma unroll
        for (int kk = 0; kk < 2; ++kk) {
            const int kc = kk * 4 + (lane >> 4);
            s16x8 af[4], bg[2], bu[2];
#pragma unroll
            for (int m = 0; m < 4; ++m) {
                const int r = wr * 64 + m * 16 + (lane & 15);
                af[m] = *(const s16x8*)(Ab + r * 128 + ((kc ^ (r & 7)) << 4));
            }
#pragma unroll
            for (int n = 0; n < 2; ++n) {
                const int rg = wc * 32 + n * 16 + (lane & 15);
                bg[n] = *(const s16x8*)(Bb + rg * 128 + ((kc ^ (rg & 7)) << 4));
                const int ru = rg + 64;
                bu[n] = *(const s16x8*)(Bb + ru * 128 + ((kc ^ (ru & 7)) << 4));
            }
#pragma unroll
            for (int m = 0; m < 4; ++m)
#pragma unroll
                for (int n = 0; n < 2; ++n) {
                    acc_g[m][n] = __builtin_amdgcn_mfma_f32_16x16x32_bf16(af[m], bg[n], acc_g[m][n], 0, 0, 0);
                    acc_u[m][n] = __builtin_amdgcn_mfma_f32_16x16x32_bf16(af[m], bu[n], acc_u[m][n], 0, 0, 0);
                }
        }
    }

    // epilogue: act = silu(g)*u, store bf16
#pragma unroll
    for (int m = 0; m < 4; ++m)
#pragma unroll
        for (int n = 0; n < 2; ++n) {
            const int col = bx * 64 + wc * 32 + n * 16 + (lane & 15);
#pragma unroll
            for (int i = 0; i < 4; ++i) {
                const int rl = wr * 64 + m * 16 + ((lane >> 4) << 2) + i;
                const int rr = by * 128 + rl;
                if (rr < n_e) {
                    const float g = acc_g[m][n][i];
                    const float u = acc_u[m][n][i];
                    const float a = (g / (1.f + __expf(-g))) * u;
                    act[(size_t)(row0 + rr) * FF + col] = (unsigned short)f2bf(a);
                }
            }
        }
}

// ---------------- GEMM2: out[t] += w_slot * act_row @ down^T ----------------
// tile: 128 rows x 128 out-cols, BK=64, K-total=F=512
// grid: (D/128, 128, NE); block: 256 threads = 4 waves (2x2)
__global__ __launch_bounds__(256) void moe_gemm2(
    const unsigned short* __restrict__ act,
    const float* __restrict__ down,      // [E, D, F]
    const int*   __restrict__ row_slot,
    const int*   __restrict__ offsets,
    const float* __restrict__ tkw,       // [T, K] flat
    float* __restrict__ out)             // [T, D], pre-zeroed
{
    const int e    = blockIdx.z;
    const int row0 = offsets[e];
    const int n_e  = offsets[e + 1] - row0;
    const int by   = blockIdx.y;
    if (by * 128 >= n_e) return;
    const int bx   = blockIdx.x;

    __shared__ __align__(16) unsigned short Abuf[128 * 64];
    __shared__ __align__(16) unsigned short Bbuf[128 * 64];
    char* Ab = (char*)Abuf; char* Bb = (char*)Bbuf;

    const int tid  = threadIdx.x;
    const int lane = tid & 63;
    const int wv   = tid >> 6;
    const int wr   = wv >> 1, wc = wv & 1;

    const unsigned short* aptr[4]; const float* bptr[4]; int soff[4];
#pragma unroll
    for (int i = 0; i < 4; ++i) {
        const int chunk = tid + i * 256;
        const int r = chunk >> 3, c = chunk & 7;
        soff[i] = r * 128 + ((c ^ (r & 7)) << 4);
        int rr = by * 128 + r; if (rr >= n_e) rr = n_e - 1;
        aptr[i] = act + (size_t)(row0 + rr) * FF + c * 8;
        bptr[i] = down + (size_t)e * (DIM * FF) + (size_t)(bx * 128 + r) * FF + c * 8;
    }

    const f32x4 zf = {0.f, 0.f, 0.f, 0.f};
    f32x4 acc[4][4];
#pragma unroll
    for (int m = 0; m < 4; ++m)
#pragma unroll
        for (int n = 0; n < 4; ++n) acc[m][n] = zf;

    for (int k0 = 0; k0 < FF; k0 += 64) {
        __syncthreads();
#pragma unroll
        for (int i = 0; i < 4; ++i) *(int4*)(Ab + soff[i]) = *(const int4*)(aptr[i] + k0); // bf16 direct
#pragma unroll
        for (int i = 0; i < 4; ++i) *(int4*)(Bb + soff[i]) = cvt8(bptr[i] + k0);           // f32 -> bf16
        __syncthreads();

#pragma unroll
        for (int kk = 0; kk < 2; ++kk) {
            const int kc = kk * 4 + (lane >> 4);
            s16x8 af[4], bf[4];
#pragma unroll
            for (int m = 0; m < 4; ++m) {
                const int r = wr * 64 + m * 16 + (lane & 15);
                af[m] = *(const s16x8*)(Ab + r * 128 + ((kc ^ (r & 7)) << 4));
            }
#pragma unroll
            for (int n = 0; n < 4; ++n) {
                const int r = wc * 64 + n * 16 + (lane & 15);
                bf[n] = *(const s16x8*)(Bb + r * 128 + ((kc ^ (r & 7)) << 4));
            }
#pragma unroll
            for (int m = 0; m < 4; ++m)
#pragma unroll
                for (int n = 0; n < 4; ++n)
                    acc[m][n] = __builtin_amdgcn_mfma_f32_16x16x32_bf16(af[m], bf[n], acc[m][n], 0, 0, 0);
        }
    }

    // epilogue: scale by slot weight, atomic-add into out
#pragma unroll
    for (int m = 0; m < 4; ++m)
#pragma unroll
        for (int i = 0; i < 4; ++i) {
            const int rl = wr * 64 + m * 16 + ((lane >> 4) << 2) + i;
            const int rr = by * 128 + rl;
            if (rr < n_e) {
                const int slot = row_slot[row0 + rr];
                const float w  = tkw[slot];
                float* orow = out + (size_t)(slot >> 1) * DIM + bx * 128 + wc * 64 + (lane & 15);
#pragma unroll
                for (int n = 0; n < 4; ++n)
                    unsafeAtomicAdd(orow + n * 16, acc[m][n][i] * w);
            }
        }
}

extern "C" void kernel_launch(void* const* d_in, const int* in_sizes, int n_in,
                              void* d_out, int out_size, void* d_ws, size_t ws_size,
                              hipStream_t stream)
{
    const float* hidden = (const float*)d_in[0];
    const int*   idx    = (const int*)  d_in[1];
    const float* tkw    = (const float*)d_in[2];
    const float* gup    = (const float*)d_in[3];
    const float* down   = (const float*)d_in[4];
    float* out = (float*)d_out;

    // workspace layout (~17 MB total)
    char* ws = (char*)d_ws;
    unsigned short* act = (unsigned short*)ws;                       // NSLOT*FF bf16 = 16 MB
    int* row_slot = (int*)(ws + (size_t)NSLOT * FF * 2);             // 64 KB
    int* ctrl     = (int*)(ws + (size_t)NSLOT * FF * 2 + NSLOT * 4);
    int* counts   = ctrl;        // [8]
    int* cursor   = ctrl + 8;    // [8]
    int* offsets  = ctrl + 16;   // [9]

    hipMemsetAsync(out, 0, (size_t)T_TOK * DIM * sizeof(float), stream);
    hipMemsetAsync(ctrl, 0, 16 * sizeof(int), stream);

    route_count  <<<NSLOT / 256, 256, 0, stream>>>(idx, counts);
    route_scan   <<<1, 64, 0, stream>>>(counts, offsets, cursor);
    route_scatter<<<NSLOT / 256, 256, 0, stream>>>(idx, cursor, row_slot);

    moe_gemm1<<<dim3(FF / 64, 128, NE), 256, 0, stream>>>(hidden, gup, row_slot, offsets, act);
    moe_gemm2<<<dim3(DIM / 128, 128, NE), 256, 0, stream>>>(act, down, row_slot, offsets, tkw, out);
}